// Round 5
// baseline (1084.870 us; speedup 1.0000x reference)
//
#include <hip/hip_runtime.h>

#define D_   256
#define HW_  1024
#define N_   32768
#define K_   1024
#define PB   16
#define ZROW 260

// ---------------------------------------------------------------------------
// numpy pairwise fp32 sum of squares over a 256-element run (stride in elems).
// Exactly mirrors numpy's pairwise_sum: n=256 -> two 128-blocks, each with
// 8 accumulators x 16 rounds and the fixed combine tree, blocks then added.
// All ops via __fmul_rn/__fadd_rn so the compiler cannot contract/reassociate.
// ---------------------------------------------------------------------------
__device__ __forceinline__ float np_sumsq_256(const float* a, int stride) {
    float blk[2];
    #pragma unroll
    for (int h = 0; h < 2; ++h) {
        const float* p = a + (size_t)h * 128 * stride;
        float r[8];
        #pragma unroll
        for (int j = 0; j < 8; ++j) {
            float v = p[(size_t)j * stride];
            r[j] = __fmul_rn(v, v);
        }
        for (int i = 1; i < 16; ++i) {
            #pragma unroll
            for (int j = 0; j < 8; ++j) {
                float v = p[(size_t)(i * 8 + j) * stride];
                r[j] = __fadd_rn(r[j], __fmul_rn(v, v));
            }
        }
        blk[h] = __fadd_rn(__fadd_rn(__fadd_rn(r[0], r[1]), __fadd_rn(r[2], r[3])),
                           __fadd_rn(__fadd_rn(r[4], r[5]), __fadd_rn(r[6], r[7])));
    }
    return __fadd_rn(blk[0], blk[1]);
}

// B32[k] = np-fp32 sum(cb[k]^2)
__global__ __launch_bounds__(256) void bnorm_kernel(const float* __restrict__ cb,
                                                    float* __restrict__ B32) {
    int k = blockIdx.x * 256 + threadIdx.x;
    if (k < K_) B32[k] = np_sumsq_256(cb + (size_t)k * D_, 1);
}

// A32[n] = np-fp32 sum(zf[n]^2)  (zf row n strided by HW in z_e's NCHW layout)
__global__ __launch_bounds__(256) void anorm_kernel(const float* __restrict__ z,
                                                    float* __restrict__ A32) {
    int n  = blockIdx.x * 256 + threadIdx.x;
    int b  = n >> 10;
    int hw = n & 1023;
    A32[n] = np_sumsq_256(z + (size_t)b * (D_ * HW_) + hw, HW_);
}

// ---------------------------------------------------------------------------
// Emulated-np argmin: d32(n,k) = fsub_rn(fadd_rn(A32[n],B32[k]), 2*C32) where
// C32 = fp32(exact fp64 dot). First-occurrence tie-break (lexicographic (v,k)).
// Block: 256 threads = 16 pixels x 16 code-groups; thread scans k ascending.
// ---------------------------------------------------------------------------
__global__ __launch_bounds__(256) void vq_np(const float* __restrict__ z,
                                             const float* __restrict__ cb,
                                             const float* __restrict__ A32,
                                             const float* __restrict__ B32,
                                             float* __restrict__ oidx) {
    __shared__ float zt[PB][ZROW];
    __shared__ float Bs[K_];
    __shared__ float rv[256];
    __shared__ int   rk[256];

    const int tid = threadIdx.x;
    const int p   = tid & 15;
    const int kg  = tid >> 4;

    const int p0  = blockIdx.x * PB;
    const int b   = p0 >> 10;
    const int hw0 = p0 & 1023;

    #pragma unroll
    for (int r = 0; r < 16; ++r) {
        int d = kg * 16 + r;
        zt[p][d] = z[(size_t)b * (D_ * HW_) + (size_t)d * HW_ + hw0 + p];
    }
    #pragma unroll
    for (int r = 0; r < 4; ++r) Bs[r * 256 + tid] = B32[r * 256 + tid];
    __syncthreads();

    const float4* zrow = reinterpret_cast<const float4*>(&zt[p][0]);
    const float An = A32[p0 + p];

    float bd = 3.4e38f;
    int   bk = 0x7fffffff;
    for (int k = kg; k < K_; k += 16) {
        const float4* crow = reinterpret_cast<const float4*>(cb + (size_t)k * D_);
        double a0 = 0.0, a1 = 0.0, a2 = 0.0, a3 = 0.0;
        #pragma unroll 8
        for (int d4 = 0; d4 < 64; ++d4) {
            float4 c4 = crow[d4];
            float4 z4 = zrow[d4];
            a0 = fma((double)c4.x, (double)z4.x, a0);
            a1 = fma((double)c4.y, (double)z4.y, a1);
            a2 = fma((double)c4.z, (double)z4.z, a2);
            a3 = fma((double)c4.w, (double)z4.w, a3);
        }
        float C32 = (float)((a0 + a1) + (a2 + a3));
        float t   = __fadd_rn(An, Bs[k]);
        float d32 = __fsub_rn(t, __fadd_rn(C32, C32));
        if (d32 < bd) { bd = d32; bk = k; }     // ascending k: first wins
    }
    rv[tid] = bd;
    rk[tid] = bk;
    __syncthreads();

    // per-pixel lexicographic merge over the 16 code groups
    if (tid < PB) {
        float m1 = 3.4e38f;
        int   q1 = 0x7fffffff;
        #pragma unroll
        for (int t = 0; t < 16; ++t) {
            float v  = rv[t * 16 + tid];
            int   kk = rk[t * 16 + tid];
            if (v < m1 || (v == m1 && kk < q1)) { m1 = v; q1 = kk; }
        }
        oidx[p0 + tid] = (float)q1;
    }
}

// ---------------------------------------------------------------------------
// z_q gather: zq[b][d][hw] = cb[idx[n]][d], coalesced per-d-plane stores.
// ---------------------------------------------------------------------------
__global__ __launch_bounds__(256) void gather_kernel(const float* __restrict__ cb,
                                                     const float* __restrict__ oidx,
                                                     float* __restrict__ zq) {
    const int tid  = threadIdx.x;
    const int s_nl = tid & 63;
    const int s_dw = tid >> 6;
    const int p0   = blockIdx.x * 64;
    const int b    = p0 >> 10;
    const int hw0  = p0 & 1023;

    int idxn = (int)oidx[p0 + s_nl];
    const float4* crow = reinterpret_cast<const float4*>(cb + (size_t)idxn * D_);
    float* zqb = zq + (size_t)b * (D_ * HW_) + hw0;
    #pragma unroll
    for (int r = 0; r < 16; ++r) {
        int d4 = s_dw * 16 + r;
        float4 c4 = crow[d4];
        int d = d4 * 4;
        zqb[(size_t)(d + 0) * HW_ + s_nl] = c4.x;
        zqb[(size_t)(d + 1) * HW_ + s_nl] = c4.y;
        zqb[(size_t)(d + 2) * HW_ + s_nl] = c4.z;
        zqb[(size_t)(d + 3) * HW_ + s_nl] = c4.w;
    }
}

extern "C" void kernel_launch(void* const* d_in, const int* in_sizes, int n_in,
                              void* d_out, int out_size, void* d_ws, size_t ws_size,
                              hipStream_t stream) {
    const float* z  = (const float*)d_in[0];   // [32,256,32,32] fp32
    const float* cb = (const float*)d_in[1];   // [1024,256] fp32

    float* zq   = (float*)d_out;               // 8388608 floats
    float* oidx = zq + (size_t)N_ * D_;        // 32768 floats (indices)

    // Scratch lives in the z_q region of d_out: written before vq_np reads it,
    // fully overwritten by gather_kernel afterwards. Deterministic each call.
    float* A32 = zq;                           // 32768 floats
    float* B32 = zq + N_;                      // 1024 floats

    bnorm_kernel<<<K_ / 256, 256, 0, stream>>>(cb, B32);
    anorm_kernel<<<N_ / 256, 256, 0, stream>>>(z, A32);
    vq_np<<<N_ / PB, 256, 0, stream>>>(z, cb, A32, B32, oidx);
    gather_kernel<<<N_ / 64, 256, 0, stream>>>(cb, oidx, zq);
}

// Round 6
// 391.250 us; speedup vs baseline: 2.7728x; 2.7728x over previous
//
#include <hip/hip_runtime.h>

#define D_   256
#define HW_  1024
#define N_   32768
#define K_   1024

#define TN   64      // pixels per block (screening)
#define KC   128     // code chunk
#define DC   64      // depth chunk

#define MAXREF  8192
#define QMARGIN 4.0e-5f   // s-units; covers d32 noise band (<=6.2e-5 d-units) + slack

// ---------------------------------------------------------------------------
// numpy pairwise fp32 sum of squares over 256 elements (stride in elems):
// two 128-blocks (8 accumulators x 16 rounds, fixed combine tree), then added.
// __fmul_rn/__fadd_rn prevent FMA contraction/reassociation.
// ---------------------------------------------------------------------------
__device__ __forceinline__ float np_sumsq_256(const float* a, int stride) {
    float blk[2];
    #pragma unroll
    for (int h = 0; h < 2; ++h) {
        const float* p = a + (size_t)h * 128 * stride;
        float r[8];
        #pragma unroll
        for (int j = 0; j < 8; ++j) {
            float v = p[(size_t)j * stride];
            r[j] = __fmul_rn(v, v);
        }
        for (int i = 1; i < 16; ++i) {
            #pragma unroll
            for (int j = 0; j < 8; ++j) {
                float v = p[(size_t)(i * 8 + j) * stride];
                r[j] = __fadd_rn(r[j], __fmul_rn(v, v));
            }
        }
        blk[h] = __fadd_rn(__fadd_rn(__fadd_rn(r[0], r[1]), __fadd_rn(r[2], r[3])),
                           __fadd_rn(__fadd_rn(r[4], r[5]), __fadd_rn(r[6], r[7])));
    }
    return __fadd_rn(blk[0], blk[1]);
}

__global__ __launch_bounds__(256) void bnorm_kernel(const float* __restrict__ cb,
                                                    float* __restrict__ B32) {
    int k = blockIdx.x * 256 + threadIdx.x;
    if (k < K_) B32[k] = np_sumsq_256(cb + (size_t)k * D_, 1);
}

__global__ __launch_bounds__(256) void anorm_kernel(const float* __restrict__ z,
                                                    float* __restrict__ A32) {
    int n  = blockIdx.x * 256 + threadIdx.x;
    int b  = n >> 10;
    int hw = n & 1023;
    A32[n] = np_sumsq_256(z + (size_t)b * (D_ * HW_) + hw, HW_);
}

__global__ __launch_bounds__(64) void init_kernel(int* counter) {
    if (threadIdx.x == 0) *counter = 0;
}

// ---------------------------------------------------------------------------
// fp32 screening: s(n,k) = 0.5*B32[k] - z_n.c_k  (d32 = A + 2s + noise).
// Tracks top-2 per pixel; flags pixels with v2-v1 < QMARGIN for refinement.
// Block: 256 threads, 64 pixels, all K in chunks of 128; 4x8 micro-tile.
// ---------------------------------------------------------------------------
__global__ __launch_bounds__(256) void vq_screen(const float* __restrict__ z,
                                                 const float* __restrict__ cb,
                                                 const float* __restrict__ B32,
                                                 float* __restrict__ oidx,
                                                 int* __restrict__ counter,
                                                 int* __restrict__ list) {
    __shared__ float zt[TN][DC + 1];     // [64][65]
    __shared__ float cbT[DC][KC + 1];    // [64][129] (transposed: [d][k'])

    const int tid = threadIdx.x;
    const int tn  = tid & 15;
    const int tk  = tid >> 4;

    const int p0  = blockIdx.x * TN;
    const int b   = p0 >> 10;
    const int hw0 = p0 & 1023;

    const float* zb = z + (size_t)b * (D_ * HW_) + hw0;

    const int s_nl = tid & 63;
    const int s_dw = tid >> 6;
    const int s_tx = tid & 15;
    const int s_ky = tid >> 4;

    float bestv[4], bestv2[4];
    int   bestk[4];
    #pragma unroll
    for (int i = 0; i < 4; ++i) { bestv[i] = 3.4e38f; bestv2[i] = 3.4e38f; bestk[i] = 0; }

    for (int k0 = 0; k0 < K_; k0 += KC) {
        float acc[4][8];
        #pragma unroll
        for (int j = 0; j < 8; ++j) {
            float c = 0.5f * B32[k0 + tk * 8 + j];
            #pragma unroll
            for (int i = 0; i < 4; ++i) acc[i][j] = c;
        }

        for (int dc = 0; dc < D_; dc += DC) {
            __syncthreads();
            #pragma unroll
            for (int r = 0; r < 16; ++r) {
                int d = s_dw * 16 + r;
                zt[s_nl][d] = zb[(size_t)(dc + d) * HW_ + s_nl];
            }
            #pragma unroll
            for (int pass = 0; pass < 8; ++pass) {
                int kk = pass * 16 + s_ky;
                float4 v = *reinterpret_cast<const float4*>(
                    cb + (size_t)(k0 + kk) * D_ + dc + s_tx * 4);
                cbT[s_tx * 4 + 0][kk] = v.x;
                cbT[s_tx * 4 + 1][kk] = v.y;
                cbT[s_tx * 4 + 2][kk] = v.z;
                cbT[s_tx * 4 + 3][kk] = v.w;
            }
            __syncthreads();
            #pragma unroll 4
            for (int d = 0; d < DC; ++d) {
                float za[4];
                #pragma unroll
                for (int i = 0; i < 4; ++i) za[i] = zt[tn * 4 + i][d];
                #pragma unroll
                for (int j = 0; j < 8; ++j) {
                    float cv = cbT[d][tk * 8 + j];
                    #pragma unroll
                    for (int i = 0; i < 4; ++i)
                        acc[i][j] = fmaf(-za[i], cv, acc[i][j]);
                }
            }
        }

        #pragma unroll
        for (int i = 0; i < 4; ++i) {
            #pragma unroll
            for (int j = 0; j < 8; ++j) {
                int kg = k0 + tk * 8 + j;
                float v = acc[i][j];
                if (v < bestv[i]) {
                    bestv2[i] = bestv[i]; bestv[i] = v; bestk[i] = kg;
                } else if (v < bestv2[i]) {
                    bestv2[i] = v;
                }
            }
        }
    }

    // cross-thread merge of (v1,k1,v2) triples over 16 code-groups
    __syncthreads();
    float* red = &cbT[0][0];
    #pragma unroll
    for (int i = 0; i < 4; ++i) {
        int n = tn * 4 + i;
        int base = n * 48 + tk * 3;
        red[base + 0] = bestv[i];
        red[base + 1] = __int_as_float(bestk[i]);
        red[base + 2] = bestv2[i];
    }
    __syncthreads();
    if (tid < TN) {
        int n = tid;
        float bv1 = 3.4e38f, bv2 = 3.4e38f; int bk1 = 0x7fffffff;
        #pragma unroll
        for (int t = 0; t < 16; ++t) {
            float v1 = red[n * 48 + t * 3 + 0];
            int   k1 = __float_as_int(red[n * 48 + t * 3 + 1]);
            float v2 = red[n * 48 + t * 3 + 2];
            if (v1 < bv1 || (v1 == bv1 && k1 < bk1)) {
                bv2 = fminf(bv1, v2); bv1 = v1; bk1 = k1;
            } else {
                bv2 = fminf(bv2, v1);
            }
        }
        oidx[p0 + n] = (float)bk1;
        if (bv2 - bv1 < QMARGIN) {
            int slot = atomicAdd(counter, 1);
            if (slot < MAXREF) list[slot] = p0 + n;
        }
    }
}

// ---------------------------------------------------------------------------
// Refinement for flagged pixels: recompute fp32 s for all K, then np-emulate
// d32 = fsub_rn(fadd_rn(A32,B32), 2*fp32(fp64 dot)) ONLY for near-min codes;
// lexicographic (d32, k) argmin = numpy first-occurrence semantics.
// ---------------------------------------------------------------------------
__global__ __launch_bounds__(256) void refine_np(const float* __restrict__ z,
                                                 const float* __restrict__ cb,
                                                 const float* __restrict__ A32,
                                                 const float* __restrict__ B32,
                                                 const int* __restrict__ counter,
                                                 const int* __restrict__ list,
                                                 float* __restrict__ oidx) {
    __shared__ float zs[D_];
    __shared__ float rmin[256];
    __shared__ float rv[256];
    __shared__ int   rk[256];

    const int tid = threadIdx.x;
    int cnt = *counter;
    if (cnt > MAXREF) cnt = MAXREF;

    for (int i = blockIdx.x; i < cnt; i += gridDim.x) {
        int n  = list[i];
        int b  = n >> 10;
        int hw = n & 1023;
        __syncthreads();
        zs[tid] = z[(size_t)b * (D_ * HW_) + (size_t)tid * HW_ + hw];
        __syncthreads();

        const float4* z4p = reinterpret_cast<const float4*>(zs);

        // phase 1: fp32 s for this thread's 4 codes
        float s4[4];
        float smin = 3.4e38f;
        #pragma unroll
        for (int jj = 0; jj < 4; ++jj) {
            int k = tid * 4 + jj;
            const float4* crow = reinterpret_cast<const float4*>(cb + (size_t)k * D_);
            float a0 = 0.f, a1 = 0.f, a2 = 0.f, a3 = 0.f;
            #pragma unroll 8
            for (int d4 = 0; d4 < 64; ++d4) {
                float4 c4 = crow[d4];
                float4 z4 = z4p[d4];
                a0 = fmaf(c4.x, z4.x, a0);
                a1 = fmaf(c4.y, z4.y, a1);
                a2 = fmaf(c4.z, z4.z, a2);
                a3 = fmaf(c4.w, z4.w, a3);
            }
            float s = 0.5f * B32[k] - ((a0 + a1) + (a2 + a3));
            s4[jj] = s;
            smin = fminf(smin, s);
        }
        rmin[tid] = smin;
        __syncthreads();
        for (int st = 128; st > 0; st >>= 1) {
            if (tid < st) rmin[tid] = fminf(rmin[tid], rmin[tid + st]);
            __syncthreads();
        }
        float smin_all = rmin[0];

        // phase 2: np-emulate d32 for qualifying codes only
        float An = A32[n];
        float bd = 3.4e38f;
        int   bk = 0x7fffffff;
        #pragma unroll
        for (int jj = 0; jj < 4; ++jj) {
            int k = tid * 4 + jj;
            if (s4[jj] - smin_all < QMARGIN) {
                const float4* crow = reinterpret_cast<const float4*>(cb + (size_t)k * D_);
                double a0 = 0.0, a1 = 0.0, a2 = 0.0, a3 = 0.0;
                #pragma unroll 8
                for (int d4 = 0; d4 < 64; ++d4) {
                    float4 c4 = crow[d4];
                    float4 z4 = z4p[d4];
                    a0 = fma((double)c4.x, (double)z4.x, a0);
                    a1 = fma((double)c4.y, (double)z4.y, a1);
                    a2 = fma((double)c4.z, (double)z4.z, a2);
                    a3 = fma((double)c4.w, (double)z4.w, a3);
                }
                float C32 = (float)((a0 + a1) + (a2 + a3));
                float d32 = __fsub_rn(__fadd_rn(An, B32[k]), __fadd_rn(C32, C32));
                if (d32 < bd) { bd = d32; bk = k; }   // ascending k: first wins
            }
        }
        rv[tid] = bd; rk[tid] = bk;
        __syncthreads();
        for (int st = 128; st > 0; st >>= 1) {
            if (tid < st) {
                float ov = rv[tid + st]; int ok = rk[tid + st];
                if (ov < rv[tid] || (ov == rv[tid] && ok < rk[tid])) {
                    rv[tid] = ov; rk[tid] = ok;
                }
            }
            __syncthreads();
        }
        if (tid == 0) oidx[n] = (float)rk[0];
    }
}

// ---------------------------------------------------------------------------
__global__ __launch_bounds__(256) void gather_kernel(const float* __restrict__ cb,
                                                     const float* __restrict__ oidx,
                                                     float* __restrict__ zq) {
    const int tid  = threadIdx.x;
    const int s_nl = tid & 63;
    const int s_dw = tid >> 6;
    const int p0   = blockIdx.x * 64;
    const int b    = p0 >> 10;
    const int hw0  = p0 & 1023;

    int idxn = (int)oidx[p0 + s_nl];
    const float4* crow = reinterpret_cast<const float4*>(cb + (size_t)idxn * D_);
    float* zqb = zq + (size_t)b * (D_ * HW_) + hw0;
    #pragma unroll
    for (int r = 0; r < 16; ++r) {
        int d4 = s_dw * 16 + r;
        float4 c4 = crow[d4];
        int d = d4 * 4;
        zqb[(size_t)(d + 0) * HW_ + s_nl] = c4.x;
        zqb[(size_t)(d + 1) * HW_ + s_nl] = c4.y;
        zqb[(size_t)(d + 2) * HW_ + s_nl] = c4.z;
        zqb[(size_t)(d + 3) * HW_ + s_nl] = c4.w;
    }
}

extern "C" void kernel_launch(void* const* d_in, const int* in_sizes, int n_in,
                              void* d_out, int out_size, void* d_ws, size_t ws_size,
                              hipStream_t stream) {
    const float* z  = (const float*)d_in[0];   // [32,256,32,32] fp32
    const float* cb = (const float*)d_in[1];   // [1024,256] fp32

    float* zq   = (float*)d_out;
    float* oidx = zq + (size_t)N_ * D_;

    // np-emulated norms live in the z_q region (overwritten by gather at end)
    float* A32 = zq;            // 32768 floats
    float* B32 = zq + N_;       // 1024 floats

    char* ws = (char*)d_ws;
    int* counter = (int*)ws;
    int* list    = (int*)(ws + 64);            // MAXREF ints

    init_kernel<<<1, 64, 0, stream>>>(counter);
    bnorm_kernel<<<K_ / 256, 256, 0, stream>>>(cb, B32);
    anorm_kernel<<<N_ / 256, 256, 0, stream>>>(z, A32);
    vq_screen<<<N_ / TN, 256, 0, stream>>>(z, cb, B32, oidx, counter, list);
    refine_np<<<1024, 256, 0, stream>>>(z, cb, A32, B32, counter, list, oidx);
    gather_kernel<<<N_ / 64, 256, 0, stream>>>(cb, oidx, zq);
}

// Round 7
// 249.538 us; speedup vs baseline: 4.3475x; 1.5679x over previous
//
#include <hip/hip_runtime.h>

#define D_   256
#define HW_  1024
#define N_   32768
#define K_   1024

#define MAXREF  8192
#define QMARGIN 5.0e-5f   // s-units; d32 noise band (3.1e-5) + bf16-split screen err + slack

typedef __attribute__((ext_vector_type(8))) short short8v;  // 8 bf16 (4 VGPRs)
typedef __attribute__((ext_vector_type(4))) float f32x4;    // MFMA acc

// ws layout (bytes):
//   0       counter (int)
//   1024    list[MAXREF] ints            (32768 B)
//   33792   B32[1024] floats             (4096 B)
//   37888   A32[32768] floats            (131072 B)
//   168960  cbAhi fragments              (524288 B)
//   693248  cbAlo fragments              (524288 B)
// total ~1.16 MB

// ---------------------------------------------------------------------------
__device__ __forceinline__ unsigned short f2bf_rne(float f) {
    unsigned u = __float_as_uint(f);
    unsigned r = u + 0x7FFFu + ((u >> 16) & 1u);
    return (unsigned short)(r >> 16);
}
__device__ __forceinline__ float bf2f(unsigned short h) {
    return __uint_as_float(((unsigned)h) << 16);
}

// ---------------------------------------------------------------------------
// numpy pairwise fp32 sum of squares over 256 elements (stride in elems).
// ---------------------------------------------------------------------------
__device__ __forceinline__ float np_sumsq_256(const float* a, int stride) {
    float blk[2];
    #pragma unroll
    for (int h = 0; h < 2; ++h) {
        const float* p = a + (size_t)h * 128 * stride;
        float r[8];
        #pragma unroll
        for (int j = 0; j < 8; ++j) {
            float v = p[(size_t)j * stride];
            r[j] = __fmul_rn(v, v);
        }
        for (int i = 1; i < 16; ++i) {
            #pragma unroll
            for (int j = 0; j < 8; ++j) {
                float v = p[(size_t)(i * 8 + j) * stride];
                r[j] = __fadd_rn(r[j], __fmul_rn(v, v));
            }
        }
        blk[h] = __fadd_rn(__fadd_rn(__fadd_rn(r[0], r[1]), __fadd_rn(r[2], r[3])),
                           __fadd_rn(__fadd_rn(r[4], r[5]), __fadd_rn(r[6], r[7])));
    }
    return __fadd_rn(blk[0], blk[1]);
}

__global__ __launch_bounds__(256) void bnorm_kernel(const float* __restrict__ cb,
                                                    float* __restrict__ B32) {
    int k = blockIdx.x * 256 + threadIdx.x;
    if (k < K_) B32[k] = np_sumsq_256(cb + (size_t)k * D_, 1);
}

__global__ __launch_bounds__(256) void anorm_kernel(const float* __restrict__ z,
                                                    float* __restrict__ A32) {
    int n  = blockIdx.x * 256 + threadIdx.x;
    int b  = n >> 10;
    int hw = n & 1023;
    A32[n] = np_sumsq_256(z + (size_t)b * (D_ * HW_) + hw, HW_);
}

__global__ __launch_bounds__(64) void init_kernel(int* counter) {
    if (threadIdx.x == 0) *counter = 0;
}

// ---------------------------------------------------------------------------
// Pre-split codebook into bf16 hi/lo, laid out in MFMA A-fragment order:
// chunk c = ((kf*8 + ds)*64 + q*16 + r): holds A[k = kf*16+r][d = ds*32+q*8+j]
// so screen's a-frag load is cbA[(kf*8+ds)*64 + lane], lane = q*16+r.
// ---------------------------------------------------------------------------
__global__ __launch_bounds__(256) void cbsplit_kernel(const float* __restrict__ cb,
                                                      short* __restrict__ cbAhi,
                                                      short* __restrict__ cbAlo) {
    int c  = blockIdx.x * 256 + threadIdx.x;   // 0..32767
    int kf = c >> 9;
    int ds = (c >> 6) & 7;
    int q  = (c >> 4) & 3;
    int r  = c & 15;
    int k  = kf * 16 + r;
    int d0 = ds * 32 + q * 8;
    const float* src = cb + (size_t)k * D_ + d0;
    short8v vh, vl;
    #pragma unroll
    for (int j = 0; j < 8; ++j) {
        float f = src[j];
        unsigned short h = f2bf_rne(f);
        float hf = bf2f(h);
        unsigned short l = f2bf_rne(f - hf);
        vh[j] = (short)h;
        vl[j] = (short)l;
    }
    *reinterpret_cast<short8v*>(cbAhi + (size_t)c * 8) = vh;
    *reinterpret_cast<short8v*>(cbAlo + (size_t)c * 8) = vl;
}

// ---------------------------------------------------------------------------
// MFMA screening. Block = 256 thr (4 waves), 128 pixels; wave owns 32 px
// (2 n-frags), all 1024 codes. z b-frags live in registers (bf16 hi+lo);
// a-frags stream from fragment-ordered global (L1/L2-hot). 3-product split:
// dot ~= ahi*bhi + alo*bhi + ahi*blo.  s = 0.5*B32[k] - dot.
// Per-lane top-2 -> shfl merge; flag pixels with gap < QMARGIN.
// ---------------------------------------------------------------------------
__global__ __launch_bounds__(256) void vq_screen_mfma(
        const float* __restrict__ z,
        const short8v* __restrict__ cbAhi,
        const short8v* __restrict__ cbAlo,
        const float* __restrict__ B32,
        float* __restrict__ oidx,
        int* __restrict__ counter,
        int* __restrict__ list)
{
    __shared__ float zt[128][33];     // transpose staging, 2-way-free banks
    __shared__ float halfB[K_];

    const int tid  = threadIdx.x;
    const int lane = tid & 63;
    const int wave = tid >> 6;
    const int q    = lane >> 4;       // 0..3
    const int r    = lane & 15;

    const int p0   = blockIdx.x * 128;
    const int b    = p0 >> 10;
    const int hw0  = p0 & 1023;
    const int wpx0 = wave * 32;

    #pragma unroll
    for (int i = 0; i < 4; ++i) halfB[i * 256 + tid] = 0.5f * B32[i * 256 + tid];

    // ---- build register-resident z b-frags (bf16 hi/lo split) ----
    short8v bhf[2][8], blf[2][8];
    for (int ds = 0; ds < 8; ++ds) {
        __syncthreads();
        #pragma unroll
        for (int i = 0; i < 16; ++i) {
            int dd = (tid >> 7) + 2 * i;                 // 0..31
            int d  = ds * 32 + dd;
            zt[tid & 127][dd] =
                z[(size_t)b * (D_ * HW_) + (size_t)d * HW_ + hw0 + (tid & 127)];
        }
        __syncthreads();
        #pragma unroll
        for (int nf = 0; nf < 2; ++nf) {
            int px = wpx0 + nf * 16 + r;
            short8v vh, vl;
            #pragma unroll
            for (int j = 0; j < 8; ++j) {
                float f = zt[px][q * 8 + j];
                unsigned short h = f2bf_rne(f);
                float hf = bf2f(h);
                unsigned short l = f2bf_rne(f - hf);
                vh[j] = (short)h;
                vl[j] = (short)l;
            }
            bhf[nf][ds] = vh;
            blf[nf][ds] = vl;
        }
    }
    __syncthreads();

    // ---- main k-loop: no LDS traffic, no full barriers ----
    float v1[2] = {3.4e38f, 3.4e38f};
    float v2[2] = {3.4e38f, 3.4e38f};
    int   k1[2] = {0, 0};

    for (int ch = 0; ch < 32; ++ch) {
        f32x4 acc00 = {0.f,0.f,0.f,0.f}, acc01 = {0.f,0.f,0.f,0.f};
        f32x4 acc10 = {0.f,0.f,0.f,0.f}, acc11 = {0.f,0.f,0.f,0.f};

        #pragma unroll
        for (int ds = 0; ds < 8; ++ds) {
            int base0 = ((ch * 2 + 0) * 8 + ds) * 64 + lane;
            int base1 = ((ch * 2 + 1) * 8 + ds) * 64 + lane;
            short8v a0h = cbAhi[base0], a0l = cbAlo[base0];
            short8v a1h = cbAhi[base1], a1l = cbAlo[base1];

            acc00 = __builtin_amdgcn_mfma_f32_16x16x32_bf16(a0h, bhf[0][ds], acc00, 0,0,0);
            acc01 = __builtin_amdgcn_mfma_f32_16x16x32_bf16(a0h, bhf[1][ds], acc01, 0,0,0);
            acc10 = __builtin_amdgcn_mfma_f32_16x16x32_bf16(a1h, bhf[0][ds], acc10, 0,0,0);
            acc11 = __builtin_amdgcn_mfma_f32_16x16x32_bf16(a1h, bhf[1][ds], acc11, 0,0,0);

            acc00 = __builtin_amdgcn_mfma_f32_16x16x32_bf16(a0l, bhf[0][ds], acc00, 0,0,0);
            acc01 = __builtin_amdgcn_mfma_f32_16x16x32_bf16(a0l, bhf[1][ds], acc01, 0,0,0);
            acc10 = __builtin_amdgcn_mfma_f32_16x16x32_bf16(a1l, bhf[0][ds], acc10, 0,0,0);
            acc11 = __builtin_amdgcn_mfma_f32_16x16x32_bf16(a1l, bhf[1][ds], acc11, 0,0,0);

            acc00 = __builtin_amdgcn_mfma_f32_16x16x32_bf16(a0h, blf[0][ds], acc00, 0,0,0);
            acc01 = __builtin_amdgcn_mfma_f32_16x16x32_bf16(a0h, blf[1][ds], acc01, 0,0,0);
            acc10 = __builtin_amdgcn_mfma_f32_16x16x32_bf16(a1h, blf[0][ds], acc10, 0,0,0);
            acc11 = __builtin_amdgcn_mfma_f32_16x16x32_bf16(a1h, blf[1][ds], acc11, 0,0,0);
        }

        // extraction: D row = q*4+reg (code), col = r (pixel)
        #pragma unroll
        for (int kf = 0; kf < 2; ++kf) {
            int kbase = ch * 32 + kf * 16 + q * 4;
            #pragma unroll
            for (int reg = 0; reg < 4; ++reg) {
                float hb = halfB[kbase + reg];
                int   kk = kbase + reg;
                {   // nf = 0
                    float s = hb - ((kf == 0) ? acc00[reg] : acc10[reg]);
                    bool lt = s < v1[0];
                    v2[0] = lt ? v1[0] : fminf(v2[0], s);
                    k1[0] = lt ? kk : k1[0];
                    v1[0] = lt ? s  : v1[0];
                }
                {   // nf = 1
                    float s = hb - ((kf == 0) ? acc01[reg] : acc11[reg]);
                    bool lt = s < v1[1];
                    v2[1] = lt ? v1[1] : fminf(v2[1], s);
                    k1[1] = lt ? kk : k1[1];
                    v1[1] = lt ? s  : v1[1];
                }
            }
        }
        __builtin_amdgcn_s_barrier();   // keep waves aligned for L1 reuse
    }

    // ---- merge the 4 q-groups per pixel (lanes l, l^16, l^32, l^48) ----
    #pragma unroll
    for (int nf = 0; nf < 2; ++nf) {
        float a1 = v1[nf], a2 = v2[nf];
        int   ak = k1[nf];
        #pragma unroll
        for (int off = 16; off <= 32; off <<= 1) {
            float o1 = __shfl_xor(a1, off, 64);
            float o2 = __shfl_xor(a2, off, 64);
            int   ok = __shfl_xor(ak, off, 64);
            if (o1 < a1 || (o1 == a1 && ok < ak)) {
                a2 = fminf(a1, o2); a1 = o1; ak = ok;
            } else {
                a2 = fminf(a2, o1);
            }
        }
        if (q == 0) {
            int n = p0 + wpx0 + nf * 16 + r;
            oidx[n] = (float)ak;
            if (a2 - a1 < QMARGIN) {
                int slot = atomicAdd(counter, 1);
                if (slot < MAXREF) list[slot] = n;
            }
        }
    }
}

// ---------------------------------------------------------------------------
// Refinement (validated in R6): fp32 s for all K, then np-emulated
// d32 = fsub_rn(fadd_rn(A32,B32), 2*fp32(fp64 dot)) for near-min codes;
// lexicographic (d32, k) = numpy first-occurrence argmin.
// ---------------------------------------------------------------------------
__global__ __launch_bounds__(256) void refine_np(const float* __restrict__ z,
                                                 const float* __restrict__ cb,
                                                 const float* __restrict__ A32,
                                                 const float* __restrict__ B32,
                                                 const int* __restrict__ counter,
                                                 const int* __restrict__ list,
                                                 float* __restrict__ oidx) {
    __shared__ float zs[D_];
    __shared__ float rmin[256];
    __shared__ float rv[256];
    __shared__ int   rk[256];

    const int tid = threadIdx.x;
    int cnt = *counter;
    if (cnt > MAXREF) cnt = MAXREF;

    for (int i = blockIdx.x; i < cnt; i += gridDim.x) {
        int n  = list[i];
        int b  = n >> 10;
        int hw = n & 1023;
        __syncthreads();
        zs[tid] = z[(size_t)b * (D_ * HW_) + (size_t)tid * HW_ + hw];
        __syncthreads();

        const float4* z4p = reinterpret_cast<const float4*>(zs);

        float s4[4];
        float smin = 3.4e38f;
        #pragma unroll
        for (int jj = 0; jj < 4; ++jj) {
            int k = tid * 4 + jj;
            const float4* crow = reinterpret_cast<const float4*>(cb + (size_t)k * D_);
            float a0 = 0.f, a1 = 0.f, a2 = 0.f, a3 = 0.f;
            #pragma unroll 8
            for (int d4 = 0; d4 < 64; ++d4) {
                float4 c4 = crow[d4];
                float4 z4 = z4p[d4];
                a0 = fmaf(c4.x, z4.x, a0);
                a1 = fmaf(c4.y, z4.y, a1);
                a2 = fmaf(c4.z, z4.z, a2);
                a3 = fmaf(c4.w, z4.w, a3);
            }
            float s = 0.5f * B32[k] - ((a0 + a1) + (a2 + a3));
            s4[jj] = s;
            smin = fminf(smin, s);
        }
        rmin[tid] = smin;
        __syncthreads();
        for (int st = 128; st > 0; st >>= 1) {
            if (tid < st) rmin[tid] = fminf(rmin[tid], rmin[tid + st]);
            __syncthreads();
        }
        float smin_all = rmin[0];

        float An = A32[n];
        float bd = 3.4e38f;
        int   bk = 0x7fffffff;
        #pragma unroll
        for (int jj = 0; jj < 4; ++jj) {
            int k = tid * 4 + jj;
            if (s4[jj] - smin_all < QMARGIN) {
                const float4* crow = reinterpret_cast<const float4*>(cb + (size_t)k * D_);
                double a0 = 0.0, a1 = 0.0, a2 = 0.0, a3 = 0.0;
                #pragma unroll 8
                for (int d4 = 0; d4 < 64; ++d4) {
                    float4 c4 = crow[d4];
                    float4 z4 = z4p[d4];
                    a0 = fma((double)c4.x, (double)z4.x, a0);
                    a1 = fma((double)c4.y, (double)z4.y, a1);
                    a2 = fma((double)c4.z, (double)z4.z, a2);
                    a3 = fma((double)c4.w, (double)z4.w, a3);
                }
                float C32 = (float)((a0 + a1) + (a2 + a3));
                float d32 = __fsub_rn(__fadd_rn(An, B32[k]), __fadd_rn(C32, C32));
                if (d32 < bd) { bd = d32; bk = k; }
            }
        }
        rv[tid] = bd; rk[tid] = bk;
        __syncthreads();
        for (int st = 128; st > 0; st >>= 1) {
            if (tid < st) {
                float ov = rv[tid + st]; int ok = rk[tid + st];
                if (ov < rv[tid] || (ov == rv[tid] && ok < rk[tid])) {
                    rv[tid] = ov; rk[tid] = ok;
                }
            }
            __syncthreads();
        }
        if (tid == 0) oidx[n] = (float)rk[0];
    }
}

// ---------------------------------------------------------------------------
__global__ __launch_bounds__(256) void gather_kernel(const float* __restrict__ cb,
                                                     const float* __restrict__ oidx,
                                                     float* __restrict__ zq) {
    const int tid  = threadIdx.x;
    const int s_nl = tid & 63;
    const int s_dw = tid >> 6;
    const int p0   = blockIdx.x * 64;
    const int b    = p0 >> 10;
    const int hw0  = p0 & 1023;

    int idxn = (int)oidx[p0 + s_nl];
    const float4* crow = reinterpret_cast<const float4*>(cb + (size_t)idxn * D_);
    float* zqb = zq + (size_t)b * (D_ * HW_) + hw0;
    #pragma unroll
    for (int r = 0; r < 16; ++r) {
        int d4 = s_dw * 16 + r;
        float4 c4 = crow[d4];
        int d = d4 * 4;
        zqb[(size_t)(d + 0) * HW_ + s_nl] = c4.x;
        zqb[(size_t)(d + 1) * HW_ + s_nl] = c4.y;
        zqb[(size_t)(d + 2) * HW_ + s_nl] = c4.z;
        zqb[(size_t)(d + 3) * HW_ + s_nl] = c4.w;
    }
}

extern "C" void kernel_launch(void* const* d_in, const int* in_sizes, int n_in,
                              void* d_out, int out_size, void* d_ws, size_t ws_size,
                              hipStream_t stream) {
    const float* z  = (const float*)d_in[0];   // [32,256,32,32] fp32
    const float* cb = (const float*)d_in[1];   // [1024,256] fp32

    float* zq   = (float*)d_out;
    float* oidx = zq + (size_t)N_ * D_;

    char* ws = (char*)d_ws;
    int*    counter = (int*)(ws + 0);
    int*    list    = (int*)(ws + 1024);
    float*  B32     = (float*)(ws + 33792);
    float*  A32     = (float*)(ws + 37888);
    short*  cbAhi   = (short*)(ws + 168960);
    short*  cbAlo   = (short*)(ws + 693248);

    init_kernel<<<1, 64, 0, stream>>>(counter);
    bnorm_kernel<<<K_ / 256, 256, 0, stream>>>(cb, B32);
    anorm_kernel<<<N_ / 256, 256, 0, stream>>>(z, A32);
    cbsplit_kernel<<<128, 256, 0, stream>>>(cb, cbAhi, cbAlo);
    vq_screen_mfma<<<N_ / 128, 256, 0, stream>>>(
        z, (const short8v*)cbAhi, (const short8v*)cbAlo, B32, oidx, counter, list);
    refine_np<<<1024, 256, 0, stream>>>(z, cb, A32, B32, counter, list, oidx);
    gather_kernel<<<N_ / 64, 256, 0, stream>>>(cb, oidx, zq);
}